// Round 4
// baseline (1068.215 us; speedup 1.0000x reference)
//
#include <hip/hip_runtime.h>

// ============================================================================
// TinyTransformerBlock via split-precision bf16x3 MFMA (gfx950).
// Every GEMM: a = ah + al (bf16 RTNE split), C = ah*bh + ah*bl + al*bh
// accumulated in fp32 AGPRs via v_mfma_f32_16x16x32_bf16. Expected absmax
// vs fp32 reference ~1e-4 (dropped al*bl term ~2^-18 rel).
// GEMM: 128x128 tile, BK=32, 4 waves (2x2, each 64x64 = 4x4 frags),
// global_load_lds(16B) staging; chunk-XOR swizzle (slot ^= row&3) applied on
// the *global source* (LDS dest stays linear, per m104/m173) and the same XOR
// on ds_read offsets. XCD-aware chunked block swizzle (nwg%8==0 everywhere).
// R3 fix: workspace aliasing — ath/atl overlapped by 16MB (racy softmax
// writes -> 0.328 absmax). Layout rebuilt with disjoint phase lifetimes.
// ============================================================================

#define EPS 1e-5f
constexpr int D   = 1024;
constexpr int DFF = 4096;
constexpr int NB  = 4;
constexpr int S   = 2048;
constexpr int M   = NB * S;  // 8192

typedef __bf16 bf16x8 __attribute__((ext_vector_type(8)));
typedef float  f32x4  __attribute__((ext_vector_type(4)));

__device__ __forceinline__ ushort f2bf(float f) {  // RTNE to bf16
  uint u = __builtin_bit_cast(uint, f);
  return (ushort)((u + 0x7fffu + ((u >> 16) & 1u)) >> 16);
}
__device__ __forceinline__ float bf2f(ushort h) {
  return __builtin_bit_cast(float, (uint)h << 16);
}
__device__ __forceinline__ void split(float f, ushort& h, ushort& l) {
  h = f2bf(f);
  l = f2bf(f - bf2f(h));  // residual exact in fp32; captures next 8 bits
}

#define GLOAD16(g, l)                                                     \
  __builtin_amdgcn_global_load_lds(                                       \
      (const __attribute__((address_space(1))) void*)(g),                 \
      (__attribute__((address_space(3))) void*)(l), 16, 0, 0)

// ---------------- LayerNorm -> bf16 hi/lo ------------------------------------
__global__ __launch_bounds__(256) void ln_kernel(const float* __restrict__ x,
                                                 const float* __restrict__ w,
                                                 const float* __restrict__ b,
                                                 ushort* __restrict__ oh,
                                                 ushort* __restrict__ ol) {
  const int row = blockIdx.x;
  const int t   = threadIdx.x;
  const float4 v = reinterpret_cast<const float4*>(x + (size_t)row * D)[t];
  float s  = v.x + v.y + v.z + v.w;
  float sq = v.x * v.x + v.y * v.y + v.z * v.z + v.w * v.w;
#pragma unroll
  for (int off = 32; off > 0; off >>= 1) {
    s  += __shfl_down(s, off);
    sq += __shfl_down(sq, off);
  }
  __shared__ float red[8];
  if ((t & 63) == 0) { red[t >> 6] = s; red[(t >> 6) + 4] = sq; }
  __syncthreads();
  if (t == 0) {
    float ts = red[0] + red[1] + red[2] + red[3];
    float tq = red[4] + red[5] + red[6] + red[7];
    float mu  = ts * (1.0f / D);
    float var = tq * (1.0f / D) - mu * mu;
    red[0] = mu;
    red[1] = rsqrtf(var + EPS);
  }
  __syncthreads();
  const float mu = red[0], rs = red[1];
  const float4 wv = reinterpret_cast<const float4*>(w)[t];
  const float4 bv = reinterpret_cast<const float4*>(b)[t];
  float o0 = (v.x - mu) * rs * wv.x + bv.x;
  float o1 = (v.y - mu) * rs * wv.y + bv.y;
  float o2 = (v.z - mu) * rs * wv.z + bv.z;
  float o3 = (v.w - mu) * rs * wv.w + bv.w;
  ushort4 hh, ll;
  split(o0, hh.x, ll.x); split(o1, hh.y, ll.y);
  split(o2, hh.z, ll.z); split(o3, hh.w, ll.w);
  *reinterpret_cast<ushort4*>(oh + (size_t)row * D + t * 4) = hh;
  *reinterpret_cast<ushort4*>(ol + (size_t)row * D + t * 4) = ll;
}

// ---------------- Softmax (scale folded) -> bf16 hi/lo -----------------------
__global__ __launch_bounds__(256) void softmax_kernel(const float* __restrict__ sc,
                                                      ushort* __restrict__ oh,
                                                      ushort* __restrict__ ol) {
  const size_t row = blockIdx.x;
  const float* p = sc + row * (size_t)S;
  const int t = threadIdx.x;
  constexpr float scale = 0.03125f;  // 1/sqrt(1024)
  float4 a = reinterpret_cast<const float4*>(p)[t];
  float4 b = reinterpret_cast<const float4*>(p)[t + 256];
  a.x *= scale; a.y *= scale; a.z *= scale; a.w *= scale;
  b.x *= scale; b.y *= scale; b.z *= scale; b.w *= scale;
  float m = fmaxf(fmaxf(fmaxf(a.x, a.y), fmaxf(a.z, a.w)),
                  fmaxf(fmaxf(b.x, b.y), fmaxf(b.z, b.w)));
#pragma unroll
  for (int off = 32; off > 0; off >>= 1) m = fmaxf(m, __shfl_xor(m, off));
  __shared__ float redm[4];
  __shared__ float reds[4];
  if ((t & 63) == 0) redm[t >> 6] = m;
  __syncthreads();
  m = fmaxf(fmaxf(redm[0], redm[1]), fmaxf(redm[2], redm[3]));
  a.x = __expf(a.x - m); a.y = __expf(a.y - m);
  a.z = __expf(a.z - m); a.w = __expf(a.w - m);
  b.x = __expf(b.x - m); b.y = __expf(b.y - m);
  b.z = __expf(b.z - m); b.w = __expf(b.w - m);
  float s = a.x + a.y + a.z + a.w + b.x + b.y + b.z + b.w;
#pragma unroll
  for (int off = 32; off > 0; off >>= 1) s += __shfl_xor(s, off);
  if ((t & 63) == 0) reds[t >> 6] = s;
  __syncthreads();
  s = reds[0] + reds[1] + reds[2] + reds[3];
  const float inv = 1.0f / s;
  ushort4 ha, la, hb, lb;
  split(a.x * inv, ha.x, la.x); split(a.y * inv, ha.y, la.y);
  split(a.z * inv, ha.z, la.z); split(a.w * inv, ha.w, la.w);
  split(b.x * inv, hb.x, lb.x); split(b.y * inv, hb.y, lb.y);
  split(b.z * inv, hb.z, lb.z); split(b.w * inv, hb.w, lb.w);
  ushort* ph = oh + row * (size_t)S;
  ushort* pl = ol + row * (size_t)S;
  *reinterpret_cast<ushort4*>(ph + t * 4)        = ha;
  *reinterpret_cast<ushort4*>(ph + 1024 + t * 4) = hb;
  *reinterpret_cast<ushort4*>(pl + t * 4)        = la;
  *reinterpret_cast<ushort4*>(pl + 1024 + t * 4) = lb;
}

// ---------------- Transpose fp32 [R][C] -> bf16 hi/lo [C][R] -----------------
__global__ __launch_bounds__(256) void transpose_conv(const float* __restrict__ in,
                                                      ushort* __restrict__ oh,
                                                      ushort* __restrict__ ol,
                                                      int R, int C,
                                                      long long sIn, long long sOut) {
  __shared__ float tile[32][33];
  const int bz = blockIdx.z;
  const float* ip = in + (size_t)bz * sIn;
  ushort* ph = oh + (size_t)bz * sOut;
  ushort* pl = ol + (size_t)bz * sOut;
  const int c0 = blockIdx.x * 32, r0 = blockIdx.y * 32;
  const int tx = threadIdx.x & 31, ty = threadIdx.x >> 5;
#pragma unroll
  for (int i = 0; i < 4; ++i)
    tile[ty + 8 * i][tx] = ip[(size_t)(r0 + ty + 8 * i) * C + c0 + tx];
  __syncthreads();
#pragma unroll
  for (int i = 0; i < 4; ++i) {
    float v = tile[tx][ty + 8 * i];
    ushort h, l;
    split(v, h, l);
    const size_t o = (size_t)(c0 + ty + 8 * i) * R + r0 + tx;
    ph[o] = h;
    pl[o] = l;
  }
}

// ---------------- bf16x3 MFMA GEMM: C = A @ Bt^T (+bias/relu/res) ------------
// A: [M][K] bf16 hi/lo.  Bt: [N][K] bf16 hi/lo (i.e. B transposed).
// Output: fp32 C and/or bf16 hi/lo C (normal [M][N] layout).
template <bool HAS_BIAS, bool RELU, bool HAS_RES, bool WRITE_F32, bool EMIT_BF16>
__global__ __launch_bounds__(256, 2) void gemm_bf16x3(
    const ushort* __restrict__ Ah, const ushort* __restrict__ Al,
    const ushort* __restrict__ Bth, const ushort* __restrict__ Btl,
    const float* __restrict__ bias, const float* Res,
    float* Cf, ushort* __restrict__ Ch, ushort* __restrict__ Cl,
    int N, int K, long long sA, long long sB, long long sC) {
  __shared__ __align__(16) ushort sAh[128 * 32];
  __shared__ __align__(16) ushort sAl[128 * 32];
  __shared__ __align__(16) ushort sBh[128 * 32];
  __shared__ __align__(16) ushort sBl[128 * 32];

  const int bz = blockIdx.z;
  const size_t aof = (size_t)bz * sA, bof = (size_t)bz * sB, cof = (size_t)bz * sC;

  // XCD-aware chunked swizzle (T1); per-z nwg%8==0 for every launch here.
  const int gx = gridDim.x;
  const int nwg = gx * gridDim.y;
  int lin = blockIdx.y * gx + blockIdx.x;
  lin = (lin & 7) * (nwg >> 3) + (lin >> 3);
  const int bm = (lin / gx) * 128;
  const int bn = (lin % gx) * 128;

  const int tid = threadIdx.x, w = tid >> 6, lane = tid & 63;
  const int wr = (w >> 1) * 64, wc = (w & 1) * 64;

  // --- staging: wave w fills linear 1KB LDS chunks c0,c1 (16 rows each) ---
  const int c0 = w * 2, c1 = c0 + 1;
  const int r0 = c0 * 16 + (lane >> 2);        // tile row for chunk c0
  const int r1 = r0 + 16;                      // chunk c1 ((r1&3)==(r0&3))
  const int kc = ((lane & 3) ^ (r0 & 3)) * 8;  // inverse-swizzled k (elements)
  const size_t gA0 = aof + (size_t)(bm + r0) * K + kc;
  const size_t gA1 = aof + (size_t)(bm + r1) * K + kc;
  const size_t gB0 = bof + (size_t)(bn + r0) * K + kc;
  const size_t gB1 = bof + (size_t)(bn + r1) * K + kc;
  ushort* dA0 = sAh + c0 * 512; ushort* dA1 = sAh + c1 * 512;
  ushort* dA2 = sAl + c0 * 512; ushort* dA3 = sAl + c1 * 512;
  ushort* dB0 = sBh + c0 * 512; ushort* dB1 = sBh + c1 * 512;
  ushort* dB2 = sBl + c0 * 512; ushort* dB3 = sBl + c1 * 512;

  // --- fragment read offsets (bytes, swizzled): lane=(fr,fc) -> row, k-slot --
  const int fr = lane & 15, fc = lane >> 4;
  int aoffB[4], boffB[4];
#pragma unroll
  for (int i = 0; i < 4; ++i) {
    const int ra = wr + i * 16 + fr;
    aoffB[i] = ra * 64 + ((fc ^ (ra & 3)) * 16);
    const int rb = wc + i * 16 + fr;
    boffB[i] = rb * 64 + ((fc ^ (rb & 3)) * 16);
  }

  f32x4 acc[4][4];
  const f32x4 zero = {0.f, 0.f, 0.f, 0.f};
#pragma unroll
  for (int i = 0; i < 4; ++i)
#pragma unroll
    for (int j = 0; j < 4; ++j) acc[i][j] = zero;

  for (int kk = 0; kk < K; kk += 32) {
    GLOAD16(Ah + gA0 + kk, dA0);
    GLOAD16(Ah + gA1 + kk, dA1);
    GLOAD16(Al + gA0 + kk, dA2);
    GLOAD16(Al + gA1 + kk, dA3);
    GLOAD16(Bth + gB0 + kk, dB0);
    GLOAD16(Bth + gB1 + kk, dB1);
    GLOAD16(Btl + gB0 + kk, dB2);
    GLOAD16(Btl + gB1 + kk, dB3);
    __syncthreads();  // compiler drains vmcnt before s_barrier -> tiles ready

    bf16x8 fah[4], fal[4], fbh[4], fbl[4];
#pragma unroll
    for (int i = 0; i < 4; ++i) {
      fah[i] = __builtin_bit_cast(bf16x8,
          *reinterpret_cast<const uint4*>(reinterpret_cast<const char*>(sAh) + aoffB[i]));
      fal[i] = __builtin_bit_cast(bf16x8,
          *reinterpret_cast<const uint4*>(reinterpret_cast<const char*>(sAl) + aoffB[i]));
      fbh[i] = __builtin_bit_cast(bf16x8,
          *reinterpret_cast<const uint4*>(reinterpret_cast<const char*>(sBh) + boffB[i]));
      fbl[i] = __builtin_bit_cast(bf16x8,
          *reinterpret_cast<const uint4*>(reinterpret_cast<const char*>(sBl) + boffB[i]));
    }
    __syncthreads();  // all waves done reading before next stage overwrites

#pragma unroll
    for (int i = 0; i < 4; ++i)
#pragma unroll
      for (int j = 0; j < 4; ++j) {
        acc[i][j] = __builtin_amdgcn_mfma_f32_16x16x32_bf16(fah[i], fbh[j], acc[i][j], 0, 0, 0);
        acc[i][j] = __builtin_amdgcn_mfma_f32_16x16x32_bf16(fah[i], fbl[j], acc[i][j], 0, 0, 0);
        acc[i][j] = __builtin_amdgcn_mfma_f32_16x16x32_bf16(fal[i], fbh[j], acc[i][j], 0, 0, 0);
      }
  }

  // --- epilogue: C/D layout col=lane&15, row=(lane>>4)*4+r (m89-verified) ---
#pragma unroll
  for (int j = 0; j < 4; ++j) {
    const int col = bn + wc + j * 16 + fr;
    const float bi = HAS_BIAS ? bias[col] : 0.0f;
#pragma unroll
    for (int i = 0; i < 4; ++i) {
#pragma unroll
      for (int r = 0; r < 4; ++r) {
        const int row = bm + wr + i * 16 + fc * 4 + r;
        float o = acc[i][j][r] + bi;
        if (RELU) o = fmaxf(o, 0.0f);
        const size_t idx = cof + (size_t)row * N + col;
        if (HAS_RES) o += Res[idx];
        if (WRITE_F32) Cf[idx] = o;
        if (EMIT_BF16) {
          ushort h, l;
          split(o, h, l);
          Ch[idx] = h;
          Cl[idx] = l;
        }
      }
    }
  }
}

// ============================================================================
extern "C" void kernel_launch(void* const* d_in, const int* in_sizes, int n_in,
                              void* d_out, int out_size, void* d_ws, size_t ws_size,
                              hipStream_t stream) {
  const float* x     = (const float*)d_in[0];
  const float* ln1_w = (const float*)d_in[1];
  const float* ln1_b = (const float*)d_in[2];
  const float* Wq    = (const float*)d_in[3];
  const float* bq    = (const float*)d_in[4];
  const float* Wk    = (const float*)d_in[5];
  const float* bk    = (const float*)d_in[6];
  const float* Wv    = (const float*)d_in[7];
  const float* bv    = (const float*)d_in[8];
  const float* Wo    = (const float*)d_in[9];
  const float* bo    = (const float*)d_in[10];
  const float* W1    = (const float*)d_in[11];
  const float* b1    = (const float*)d_in[12];
  const float* W2    = (const float*)d_in[13];
  const float* b2    = (const float*)d_in[14];
  const float* ln2_w = (const float*)d_in[15];
  const float* ln2_b = (const float*)d_in[16];
  float* out = (float*)d_out;
  char* W = (char*)d_ws;

  // Workspace (MB offsets, 192MB peak). Phase lifetimes (audited disjoint):
  //  A: h1[0,32)  wq..wv[32,44)
  //  B: QKV: q[64,96) k[96,128) vf[128,160)
  //  C: vT[160,192)
  //  D: scores scf[0,64)           (h1,w* dead)
  //  E: attn ath[64,96) atl[96,128) (q,k dead)
  //  F: ctx cx[128,160)             (vf dead)
  //  G: wo[0,4) -> out              (scf dead)
  //  H: h2[32,64)                   (w* dead)
  //  I: w1[0,16) w2[16,32)          (wo dead)
  //  J: t1[64,192)                  (attn,cx,vT dead)
  auto U = [&](size_t mb) { return (ushort*)(W + (mb << 20)); };
  auto F = [&](size_t mb) { return (float*)(W + (mb << 20)); };
  ushort *h1h = U(0),   *h1l = U(16);
  ushort *wqh = U(32),  *wql = U(34);
  ushort *wkh = U(36),  *wkl = U(38);
  ushort *wvh = U(40),  *wvl = U(42);
  ushort *qh  = U(64),  *ql  = U(80);
  ushort *kh  = U(96),  *kl  = U(112);
  float  *vf  = F(128);
  ushort *vth = U(160), *vtl = U(176);
  float  *scf = F(0);
  ushort *ath = U(64),  *atl = U(96);
  ushort *cxh = U(128), *cxl = U(144);
  ushort *woh = U(0),   *wol = U(2);
  ushort *h2h = U(32),  *h2l = U(48);
  ushort *w1h = U(0),   *w1l = U(8);
  ushort *w2h = U(16),  *w2l = U(24);
  ushort *t1h = U(64),  *t1l = U(128);

  const long long SD = (long long)S * D, SS = (long long)S * S;
  dim3 tb(256);

  // QKV weight transpose+convert
  transpose_conv<<<dim3(32, 32, 1), tb, 0, stream>>>(Wq, wqh, wql, D, D, 0, 0);
  transpose_conv<<<dim3(32, 32, 1), tb, 0, stream>>>(Wk, wkh, wkl, D, D, 0, 0);
  transpose_conv<<<dim3(32, 32, 1), tb, 0, stream>>>(Wv, wvh, wvl, D, D, 0, 0);

  // h1 = LN1(x)
  ln_kernel<<<M, tb, 0, stream>>>(x, ln1_w, ln1_b, h1h, h1l);

  // q/k (bf16 out), v (fp32 out, transposed next)
  dim3 g1024(D / 128, M / 128, 1);
  gemm_bf16x3<true, false, false, false, true><<<g1024, tb, 0, stream>>>(
      h1h, h1l, wqh, wql, bq, nullptr, nullptr, qh, ql, D, D, 0, 0, 0);
  gemm_bf16x3<true, false, false, false, true><<<g1024, tb, 0, stream>>>(
      h1h, h1l, wkh, wkl, bk, nullptr, nullptr, kh, kl, D, D, 0, 0, 0);
  gemm_bf16x3<true, false, false, true, false><<<g1024, tb, 0, stream>>>(
      h1h, h1l, wvh, wvl, bv, nullptr, vf, nullptr, nullptr, D, D, 0, 0, 0);

  // vT per batch: [2048x1024] -> [1024x2048] bf16 h/l
  transpose_conv<<<dim3(D / 32, S / 32, NB), tb, 0, stream>>>(vf, vth, vtl, S, D, SD, SD);

  // scores = q @ k^T (Bt = k directly), batched
  dim3 gsc(S / 128, S / 128, NB);
  gemm_bf16x3<false, false, false, true, false><<<gsc, tb, 0, stream>>>(
      qh, ql, kh, kl, nullptr, nullptr, scf, nullptr, nullptr, S, D, SD, SD, SS);

  // attn = softmax(scores * 1/32) -> bf16 h/l
  softmax_kernel<<<M, tb, 0, stream>>>(scf, ath, atl);

  // ctx = attn @ v (Bt = vT), batched, K=2048
  dim3 gcx(D / 128, S / 128, NB);
  gemm_bf16x3<false, false, false, false, true><<<gcx, tb, 0, stream>>>(
      ath, atl, vth, vtl, nullptr, nullptr, nullptr, cxh, cxl, D, S, SS, SD, SD);

  // out = x + ctx @ Wo + bo
  transpose_conv<<<dim3(32, 32, 1), tb, 0, stream>>>(Wo, woh, wol, D, D, 0, 0);
  gemm_bf16x3<true, false, true, true, false><<<g1024, tb, 0, stream>>>(
      cxh, cxl, woh, wol, bo, x, out, nullptr, nullptr, D, D, 0, 0, 0);

  // h2 = LN2(out)
  ln_kernel<<<M, tb, 0, stream>>>(out, ln2_w, ln2_b, h2h, h2l);

  // FFN weights
  transpose_conv<<<dim3(DFF / 32, D / 32, 1), tb, 0, stream>>>(W1, w1h, w1l, D, DFF, 0, 0);
  transpose_conv<<<dim3(D / 32, DFF / 32, 1), tb, 0, stream>>>(W2, w2h, w2l, DFF, D, 0, 0);

  // t1 = relu(h2 @ W1 + b1) -> bf16 h/l only
  dim3 gf1(DFF / 128, M / 128, 1);
  gemm_bf16x3<true, true, false, false, true><<<gf1, tb, 0, stream>>>(
      h2h, h2l, w1h, w1l, b1, nullptr, nullptr, t1h, t1l, DFF, D, 0, 0, 0);

  // out = out + t1 @ W2 + b2  (K=4096)
  gemm_bf16x3<true, false, true, true, false><<<g1024, tb, 0, stream>>>(
      t1h, t1l, w2h, w2l, b2, out, out, nullptr, nullptr, D, DFF, 0, 0, 0);
}